// Round 1
// baseline (786.181 us; speedup 1.0000x reference)
//
#include <hip/hip_runtime.h>
#include <hip/hip_bf16.h>
#include <math.h>

#define T_TOK 2048
#define H_DIM 2048
#define I_DIM 1024
#define E_NUM 16
#define TOPK  4

#define BM 128
#define BN 128
#define BK 32

typedef __attribute__((ext_vector_type(8))) __bf16 bf16x8;
typedef __attribute__((ext_vector_type(4))) float  f32x4;

__device__ __forceinline__ unsigned short f2bf(float f) {
    unsigned int u = __builtin_bit_cast(unsigned int, f);
    unsigned int r = u + 0x7FFFu + ((u >> 16) & 1u);
    return (unsigned short)(r >> 16);
}

// async global->LDS DMA, 16 bytes per lane. LDS dest must be
// wave-uniform base + lane*16 (our staging layout is exactly linear in tid).
__device__ __forceinline__ void gload16(const void* g, void* l) {
    __builtin_amdgcn_global_load_lds(
        (const __attribute__((address_space(1))) unsigned int*)g,
        (__attribute__((address_space(3))) unsigned int*)l,
        16, 0, 0);
}

// ---------------- workspace layout (bytes) ----------------
// counts[16]            @ 0
// offsets[16]           @ 256
// tok[16*2048] int      @ 512        (131072 B)
// wl [16*2048] float    @ 131584     (131072 B)
// X16 [T][H] bf16       @ 262656     (8388608 B)
// w1t [E][I][H] bf16    @ 8651264    (67108864 B)
// w3t [E][I][H] bf16    @ 75760128   (67108864 B)
// w2t [E][H][I] bf16    @ 142868992  (67108864 B)
// act [8192][I] bf16    @ 209977856  (16777216 B)  -> total 226755072 B
static const size_t WS_COUNTS  = 0;
static const size_t WS_OFFSETS = 256;
static const size_t WS_TOK     = 512;
static const size_t WS_WL      = 131584;
static const size_t WS_X16     = 262656;
static const size_t WS_W1T     = 8651264;
static const size_t WS_W3T     = 75760128;
static const size_t WS_W2T     = 142868992;
static const size_t WS_ACT     = 209977856;

// ---------------- kernels ----------------

__global__ void zero_init(float* __restrict__ out, int* __restrict__ counts) {
    int i = blockIdx.x * blockDim.x + threadIdx.x;
    ((float4*)out)[i] = make_float4(0.f, 0.f, 0.f, 0.f);
    if (i < E_NUM) counts[i] = 0;
}

__global__ void convert_x(const float* __restrict__ x, unsigned short* __restrict__ X16) {
    int i = blockIdx.x * blockDim.x + threadIdx.x;
    float4 v = ((const float4*)x)[i];
    ushort4 o;
    o.x = f2bf(v.x); o.y = f2bf(v.y); o.z = f2bf(v.z); o.w = f2bf(v.w);
    ((ushort4*)X16)[i] = o;
}

// in: [E][R][C] fp32 -> out: [E][C][R] bf16
__global__ void transpose_conv(const float* __restrict__ in, unsigned short* __restrict__ out,
                               int R, int C) {
    __shared__ unsigned short tile[32][33];
    int e  = blockIdx.z;
    int c0 = blockIdx.x * 32;
    int r0 = blockIdx.y * 32;
    const float* ip = in + (size_t)e * R * C;
    unsigned short* op = out + (size_t)e * R * C;
    int t = threadIdx.x;            // 256 threads
    int r  = t >> 3;                // 0..31
    int c4 = (t & 7) * 4;           // 0,4,..28
    float4 v = *(const float4*)&ip[(size_t)(r0 + r) * C + c0 + c4];
    tile[c4 + 0][r] = f2bf(v.x);
    tile[c4 + 1][r] = f2bf(v.y);
    tile[c4 + 2][r] = f2bf(v.z);
    tile[c4 + 3][r] = f2bf(v.w);
    __syncthreads();
    // write out[c][r], contiguous in r
    ushort4 o;
    o.x = tile[r][c4 + 0];
    o.y = tile[r][c4 + 1];
    o.z = tile[r][c4 + 2];
    o.w = tile[r][c4 + 3];
    *(ushort4*)&op[(size_t)(c0 + r) * R + r0 + c4] = o;
}

__global__ void router(const float* __restrict__ x, const float* __restrict__ gw,
                       int* __restrict__ counts, int* __restrict__ tok,
                       float* __restrict__ wl) {
    int t = blockIdx.x;
    int lane = threadIdx.x;  // 64
    float acc[E_NUM];
#pragma unroll
    for (int e = 0; e < E_NUM; e++) acc[e] = 0.f;
    const float* xr = x + (size_t)t * H_DIM;
    for (int h = lane; h < H_DIM; h += 64) {
        float xv = xr[h];
#pragma unroll
        for (int e = 0; e < E_NUM; e++) acc[e] += xv * gw[e * H_DIM + h];
    }
#pragma unroll
    for (int e = 0; e < E_NUM; e++) {
#pragma unroll
        for (int off = 32; off; off >>= 1) acc[e] += __shfl_down(acc[e], off);
    }
    if (lane == 0) {
        bool used[E_NUM];
#pragma unroll
        for (int e = 0; e < E_NUM; e++) used[e] = false;
        int   idx[TOPK];
        float lv[TOPK];
        for (int k = 0; k < TOPK; k++) {
            float best = -1e30f; int bi = 0;
            for (int e = 0; e < E_NUM; e++)
                if (!used[e] && acc[e] > best) { best = acc[e]; bi = e; }
            used[bi] = true; idx[k] = bi; lv[k] = best;
        }
        // renormalized softmax over the top-4 logits
        float m = lv[0];
        float w[TOPK]; float s = 0.f;
        for (int k = 0; k < TOPK; k++) { w[k] = expf(lv[k] - m); s += w[k]; }
        float inv = 1.f / s;
        for (int k = 0; k < TOPK; k++) {
            int pos = atomicAdd(&counts[idx[k]], 1);
            tok[idx[k] * T_TOK + pos] = t;
            wl [idx[k] * T_TOK + pos] = w[k] * inv;
        }
    }
}

__global__ void prefix(const int* __restrict__ counts, int* __restrict__ offsets) {
    if (threadIdx.x == 0 && blockIdx.x == 0) {
        int s = 0;
        for (int e = 0; e < E_NUM; e++) { offsets[e] = s; s += counts[e]; }
    }
}

// stage1: act[slot][i] = silu(X@w1) * (X@w3) * route_weight,  bf16
__global__ __launch_bounds__(256, 2) void stage1(
    const unsigned short* __restrict__ X16,   // [T][H]
    const unsigned short* __restrict__ w1t,   // [E][I][H]
    const unsigned short* __restrict__ w3t,   // [E][I][H]
    const int* __restrict__ counts, const int* __restrict__ offsets,
    const int* __restrict__ tok, const float* __restrict__ wl,
    unsigned short* __restrict__ act)         // [8192][I]
{
    int e   = blockIdx.z;
    int n_e = counts[e];
    int m0  = blockIdx.y * BM;
    if (m0 >= n_e) return;
    int n0  = blockIdx.x * BN;

    __shared__ __align__(16) unsigned short As [BM][BK];
    __shared__ __align__(16) unsigned short B1s[BN][BK];
    __shared__ __align__(16) unsigned short B2s[BN][BK];

    int tid  = threadIdx.x;
    int wave = tid >> 6, lane = tid & 63;
    int wm = (wave >> 1) * 64, wn = (wave & 1) * 64;
    int lr = lane & 15, lq = lane >> 4;

    const unsigned short* w1p = w1t + (size_t)e * I_DIM * H_DIM;
    const unsigned short* w3p = w3t + (size_t)e * I_DIM * H_DIM;

    // per-thread staging coords (fixed across K): idx = rep*256+tid,
    // LDS byte offset = idx*16 -> linear in lane, as global_load_lds requires
    int ar[2]; int rr[2]; int cc[2];
#pragma unroll
    for (int rep = 0; rep < 2; rep++) {
        int idx = rep * 256 + tid;
        rr[rep] = idx >> 2;
        cc[rep] = (idx & 3) * 8;
        int gm = m0 + rr[rep];
        ar[rep] = tok[e * T_TOK + (gm < n_e ? gm : n_e - 1)];
    }

    f32x4 acc1[4][4] = {};
    f32x4 acc3[4][4] = {};

    for (int k0 = 0; k0 < H_DIM; k0 += BK) {
#pragma unroll
        for (int rep = 0; rep < 2; rep++) {
            int r = rr[rep], ch = cc[rep];
            gload16(&X16[(size_t)ar[rep] * H_DIM + k0 + ch], &As [r][ch]);
            gload16(&w1p[(size_t)(n0 + r) * H_DIM + k0 + ch], &B1s[r][ch]);
            gload16(&w3p[(size_t)(n0 + r) * H_DIM + k0 + ch], &B2s[r][ch]);
        }
        __syncthreads();   // compiler drains vmcnt(0) here -> LDS tiles ready
        bf16x8 af[4], b1f[4], b2f[4];
#pragma unroll
        for (int ti = 0; ti < 4; ti++)
            af[ti] = *(const bf16x8*)&As[wm + ti * 16 + lr][lq * 8];
#pragma unroll
        for (int tj = 0; tj < 4; tj++) {
            b1f[tj] = *(const bf16x8*)&B1s[wn + tj * 16 + lr][lq * 8];
            b2f[tj] = *(const bf16x8*)&B2s[wn + tj * 16 + lr][lq * 8];
        }
#pragma unroll
        for (int ti = 0; ti < 4; ti++)
#pragma unroll
            for (int tj = 0; tj < 4; tj++) {
                acc1[ti][tj] = __builtin_amdgcn_mfma_f32_16x16x32_bf16(af[ti], b1f[tj], acc1[ti][tj], 0, 0, 0);
                acc3[ti][tj] = __builtin_amdgcn_mfma_f32_16x16x32_bf16(af[ti], b2f[tj], acc3[ti][tj], 0, 0, 0);
            }
        __syncthreads();
    }

    int slotbase = offsets[e] + m0;
#pragma unroll
    for (int ti = 0; ti < 4; ti++) {
#pragma unroll
        for (int reg = 0; reg < 4; reg++) {
            int mrow = wm + ti * 16 + lq * 4 + reg;
            int gm = m0 + mrow;
            if (gm >= n_e) continue;
            float wt = wl[e * T_TOK + gm];
            size_t obase = (size_t)(slotbase + mrow) * I_DIM + n0;
#pragma unroll
            for (int tj = 0; tj < 4; tj++) {
                float h1 = acc1[ti][tj][reg];
                float h3 = acc3[ti][tj][reg];
                float a = (h1 / (1.f + expf(-h1))) * h3 * wt;
                act[obase + wn + tj * 16 + lr] = f2bf(a);
            }
        }
    }
}

// stage2: out[tok] += act @ w2
__global__ __launch_bounds__(256, 2) void stage2(
    const unsigned short* __restrict__ act,   // [8192][I]
    const unsigned short* __restrict__ w2t,   // [E][H][I]
    const int* __restrict__ counts, const int* __restrict__ offsets,
    const int* __restrict__ tok,
    float* __restrict__ out)                  // [T][H]
{
    int e   = blockIdx.z;
    int n_e = counts[e];
    int m0  = blockIdx.y * BM;
    if (m0 >= n_e) return;
    int n0  = blockIdx.x * BN;   // over H

    __shared__ __align__(16) unsigned short As[BM][BK];
    __shared__ __align__(16) unsigned short Bs[BN][BK];

    int tid  = threadIdx.x;
    int wave = tid >> 6, lane = tid & 63;
    int wm = (wave >> 1) * 64, wn = (wave & 1) * 64;
    int lr = lane & 15, lq = lane >> 4;

    const unsigned short* w2p = w2t + (size_t)e * H_DIM * I_DIM;
    int slotbase = offsets[e];

    // per-thread staging coords; A rows gathered (clamped), LDS dest linear
    int rr[2]; int cc[2]; int arow[2];
#pragma unroll
    for (int rep = 0; rep < 2; rep++) {
        int idx = rep * 256 + tid;
        rr[rep] = idx >> 2;
        cc[rep] = (idx & 3) * 8;
        int gm = m0 + rr[rep];
        arow[rep] = slotbase + (gm < n_e ? gm : n_e - 1);
    }

    f32x4 acc[4][4] = {};

    for (int k0 = 0; k0 < I_DIM; k0 += BK) {
#pragma unroll
        for (int rep = 0; rep < 2; rep++) {
            int r = rr[rep], ch = cc[rep];
            gload16(&act[(size_t)arow[rep] * I_DIM + k0 + ch], &As[r][ch]);
            gload16(&w2p[(size_t)(n0 + r) * I_DIM + k0 + ch], &Bs[r][ch]);
        }
        __syncthreads();
        bf16x8 af[4], bf[4];
#pragma unroll
        for (int ti = 0; ti < 4; ti++)
            af[ti] = *(const bf16x8*)&As[wm + ti * 16 + lr][lq * 8];
#pragma unroll
        for (int tj = 0; tj < 4; tj++)
            bf[tj] = *(const bf16x8*)&Bs[wn + tj * 16 + lr][lq * 8];
#pragma unroll
        for (int ti = 0; ti < 4; ti++)
#pragma unroll
            for (int tj = 0; tj < 4; tj++)
                acc[ti][tj] = __builtin_amdgcn_mfma_f32_16x16x32_bf16(af[ti], bf[tj], acc[ti][tj], 0, 0, 0);
        __syncthreads();
    }

#pragma unroll
    for (int ti = 0; ti < 4; ti++) {
#pragma unroll
        for (int reg = 0; reg < 4; reg++) {
            int mrow = wm + ti * 16 + lq * 4 + reg;
            int gm = m0 + mrow;
            if (gm >= n_e) continue;
            int tm = tok[e * T_TOK + gm];
            size_t obase = (size_t)tm * H_DIM + n0;
#pragma unroll
            for (int tj = 0; tj < 4; tj++)
                atomicAdd(&out[obase + wn + tj * 16 + lr], acc[ti][tj][reg]);
        }
    }
}

// ---------------- launch ----------------
extern "C" void kernel_launch(void* const* d_in, const int* in_sizes, int n_in,
                              void* d_out, int out_size, void* d_ws, size_t ws_size,
                              hipStream_t stream) {
    const float* x_f32 = (const float*)d_in[0];
    const float* gw    = (const float*)d_in[1];
    const float* w1    = (const float*)d_in[2];
    const float* w3    = (const float*)d_in[3];
    const float* w2    = (const float*)d_in[4];
    float* out = (float*)d_out;

    char* ws = (char*)d_ws;
    int*            counts  = (int*)(ws + WS_COUNTS);
    int*            offsets = (int*)(ws + WS_OFFSETS);
    int*            tok     = (int*)(ws + WS_TOK);
    float*          wl      = (float*)(ws + WS_WL);
    unsigned short* X16     = (unsigned short*)(ws + WS_X16);
    unsigned short* w1t     = (unsigned short*)(ws + WS_W1T);
    unsigned short* w3t     = (unsigned short*)(ws + WS_W3T);
    unsigned short* w2t     = (unsigned short*)(ws + WS_W2T);
    unsigned short* act     = (unsigned short*)(ws + WS_ACT);

    // 1. zero out + counts
    zero_init<<<dim3((T_TOK * H_DIM / 4) / 256), 256, 0, stream>>>(out, counts);
    // 2. hidden -> bf16
    convert_x<<<dim3((T_TOK * H_DIM / 4) / 256), 256, 0, stream>>>(x_f32, X16);
    // 3. weight transposes (fp32 [E][R][C] -> bf16 [E][C][R])
    transpose_conv<<<dim3(I_DIM / 32, H_DIM / 32, E_NUM), 256, 0, stream>>>(w1, w1t, H_DIM, I_DIM);
    transpose_conv<<<dim3(I_DIM / 32, H_DIM / 32, E_NUM), 256, 0, stream>>>(w3, w3t, H_DIM, I_DIM);
    transpose_conv<<<dim3(H_DIM / 32, I_DIM / 32, E_NUM), 256, 0, stream>>>(w2, w2t, I_DIM, H_DIM);
    // 4. router
    router<<<dim3(T_TOK), 64, 0, stream>>>(x_f32, gw, counts, tok, wl);
    // 5. prefix offsets
    prefix<<<dim3(1), 64, 0, stream>>>(counts, offsets);
    // 6. stage1 grouped GEMM (h1,h3 fused -> act)
    stage1<<<dim3(I_DIM / BN, T_TOK / BM, E_NUM), 256, 0, stream>>>(
        X16, w1t, w3t, counts, offsets, tok, wl, act);
    // 7. stage2 grouped GEMM -> scatter-add out
    stage2<<<dim3(H_DIM / BN, T_TOK / BM, E_NUM), 256, 0, stream>>>(
        act, w2t, counts, offsets, tok, out);
}